// Round 2
// baseline (3440.710 us; speedup 1.0000x reference)
//
#include <hip/hip_runtime.h>
#include <hip/hip_bf16.h>

#define HH 192
#define WW 192
#define HW 36864           // 192*192
#define CHW 2359296        // 64*36864

// ---------------------------------------------------------------- prep ----
// transposes (fp32 inputs, no dtype conversion needed) + tmp512 zeroing.
__global__ void k_prep(const float* __restrict__ c2w, const float* __restrict__ wfuse,
                       float* __restrict__ w2t, float* __restrict__ wfT,
                       float* __restrict__ tmp) {
  int i = blockIdx.x * 256 + threadIdx.x;
  if (i < 16384) { int oc = i >> 6, c = i & 63; w2t[i] = c2w[c * 256 + oc]; return; }
  int k = i - 16384;
  if (k < 131072) { int jj = k >> 8, r = k & 255; wfT[k] = wfuse[r * 512 + jj]; return; }
  int z = i - 147456;
  if (z >= 0 && z < 65536) tmp[z] = 0.f;
}

// ---------------------------------------------------- init polys + out0 ----
__global__ void k_init_polys(const float* __restrict__ wh, const int* __restrict__ ct_ind,
                             const int* __restrict__ ct_img,
                             float* __restrict__ initp, float* __restrict__ out0) {
  int n = blockIdx.x;     // 0..127
  int p = threadIdx.x;    // 0..127
  int ind = ct_ind[n], img = ct_img[n];
  int cx = ind % WW, cy = ind / WW;
  size_t base = ((size_t)(img * 256 + 2 * p)) * HW + (size_t)cy * WW + cx;
  float ox = wh[base];
  float oy = wh[base + HW];
  // replicate np fp32 exactly: (off*10) rounds, +ct rounds (no contraction)
  float px = __fadd_rn(__fmul_rn(ox, 10.0f), (float)cx);
  float py = __fadd_rn(__fmul_rn(oy, 10.0f), (float)cy);
  initp[n * 256 + 2 * p]     = px;
  initp[n * 256 + 2 * p + 1] = py;
  out0[n * 256 + 2 * p]      = __fmul_rn(px, 4.0f);
  out0[n * 256 + 2 * p + 1]  = __fmul_rn(py, 4.0f);
}

// ------------------------------------------------- fused conv1+relu+conv2 ----
// block = 256 threads = one 16x16 spatial tile; weights via uniform (SGPR) loads.
__global__ __launch_bounds__(256) void k_conv(const float* __restrict__ x,
    const float* __restrict__ w1, const float* __restrict__ b1,
    const float* __restrict__ w2t, const float* __restrict__ b2,
    float* __restrict__ feat) {
  int b = blockIdx.y;
  int ty0 = (blockIdx.x / 12) * 16, tx0 = (blockIdx.x % 12) * 16;
  int t = threadIdx.x;
  int ty = t >> 4, tx = t & 15;
  __shared__ float xS[16][18][19];
  float facc[64];
#pragma unroll
  for (int c = 0; c < 64; ++c) facc[c] = b2[c];
  for (int ocg = 0; ocg < 4; ++ocg) {
    float tacc[64];
#pragma unroll
    for (int j = 0; j < 64; ++j) tacc[j] = b1[ocg * 64 + j];
    for (int icc = 0; icc < 4; ++icc) {
      __syncthreads();
      for (int idx = t; idx < 16 * 324; idx += 256) {
        int ic = idx / 324; int rem = idx - ic * 324;
        int rr = rem / 18, cc = rem - rr * 18;
        int gy = ty0 + rr - 1, gx = tx0 + cc - 1;
        float v = 0.f;
        if (gy >= 0 && gy < HH && gx >= 0 && gx < WW)
          v = x[(size_t)(b * 64 + icc * 16 + ic) * HW + (size_t)gy * WW + gx];
        xS[ic][rr][cc] = v;
      }
      __syncthreads();
      for (int ic = 0; ic < 16; ++ic) {
        float xv[9];
#pragma unroll
        for (int ky = 0; ky < 3; ++ky)
#pragma unroll
          for (int kx = 0; kx < 3; ++kx)
            xv[ky * 3 + kx] = xS[ic][ty + ky][tx + kx];
        const float* wp = w1 + (size_t)(ocg * 64) * 576 + (size_t)(icc * 16 + ic) * 9;
#pragma unroll
        for (int j = 0; j < 64; ++j) {
          const float* wj = wp + (size_t)j * 576;
#pragma unroll
          for (int k = 0; k < 9; ++k) tacc[j] = fmaf(wj[k], xv[k], tacc[j]);
        }
      }
    }
#pragma unroll
    for (int j = 0; j < 64; ++j) {
      float tj = fmaxf(tacc[j], 0.f);
      const float* w2p = w2t + (size_t)(ocg * 64 + j) * 64;
#pragma unroll
      for (int c = 0; c < 64; ++c) facc[c] = fmaf(w2p[c], tj, facc[c]);
    }
  }
  int gy = ty0 + ty, gx = tx0 + tx;
  size_t base = (size_t)b * CHW + (size_t)gy * WW + gx;
#pragma unroll
  for (int c = 0; c < 64; ++c) feat[base + (size_t)c * HW] = facc[c];
}

// ------------------------------------------------------ point-in-polygon ----
// one wave per (row, poly). Only polys 0..63 are ever used by _mask_batch
// (reference slicing bug: batches 1,2,3 all get polys 32..63) — replicated.
__global__ __launch_bounds__(64) void k_pnp(const float* __restrict__ polys,
                                            float* __restrict__ outm) {
  int row  = blockIdx.x;   // 0..191
  int n    = blockIdx.y;   // 0..63
  int lane = threadIdx.x;
  __shared__ float vx[128], vy[128], xint[128];
  __shared__ int cnt;
  if (lane == 0) cnt = 0;
  vx[lane]      = polys[n * 256 + 2 * lane];
  vy[lane]      = polys[n * 256 + 2 * lane + 1];
  vx[lane + 64] = polys[n * 256 + 2 * (lane + 64)];
  vy[lane + 64] = polys[n * 256 + 2 * (lane + 64) + 1];
  __syncthreads();
  float yy = (float)row;
  for (int e = lane; e < 128; e += 64) {
    float y1 = vy[e], y2 = vy[(e + 1) & 127];
    if ((y1 > yy) != (y2 > yy)) {
      float x1 = vx[e], x2 = vx[(e + 1) & 127];
      float den = __fsub_rn(y2, y1);
      if (fabsf(den) < 1e-9f) den = 1e-9f;
      float xi = __fadd_rn(x1, __fdiv_rn(__fmul_rn(__fsub_rn(x2, x1), __fsub_rn(yy, y1)), den));
      xint[atomicAdd(&cnt, 1)] = xi;
    }
  }
  __syncthreads();
  int m = cnt;
  int bb = (n < 32) ? 0 : 1;
  int cc = n & 31;
  size_t base = ((size_t)(bb * 32 + cc) * HH + row) * WW;
  for (int xp = lane; xp < WW; xp += 64) {
    float xf = (float)xp;
    int c = 0;
    for (int j = 0; j < m; ++j) c += (xf < xint[j]) ? 1 : 0;
    float mv = (float)(c & 1);
    outm[base + xp] = mv;
    if (n >= 32) {                       // duplicate into batches 2 and 3
      outm[base + (size_t)32 * HW + xp] = mv;
      outm[base + (size_t)64 * HW + xp] = mv;
    }
  }
}

// ------------------------------------------------------------ union mask ----
__global__ void k_union(const float* __restrict__ m, float* __restrict__ u) {
  int i = blockIdx.x * 256 + threadIdx.x;   // 4*HW
  if (i >= 4 * HW) return;
  int b = i / HW, yx = i - b * HW;
  const float* p = m + (size_t)b * 32 * HW + yx;
  float mx = 0.f;
  for (int c = 0; c < 32; ++c) mx = fmaxf(mx, p[(size_t)c * HW]);
  u[i] = mx;
}

// --------------------------------------------- feat = relu(u*f + f), inplace ----
__global__ void k_maskrelu(float* __restrict__ feat, const float* __restrict__ u) {
  size_t i = (size_t)blockIdx.x * 256 + threadIdx.x;  // 9437184
  int b = (int)(i / ((size_t)CHW));
  int yx = (int)(i % HW);
  float f = feat[i];
  float uu = u[b * HW + yx];
  feat[i] = fmaxf(__fadd_rn(__fmul_rn(uu, f), f), 0.f);
}

// ------------------------------------------------------- bilinear sample ----
// one wave per (poly, point); lane = channel. fp[n, c*129 + p].
__global__ __launch_bounds__(64) void k_sample(const float* __restrict__ feat,
    const float* __restrict__ initp, const int* __restrict__ ct_ind,
    const int* __restrict__ ct_img, float* __restrict__ fp) {
  int blk = blockIdx.x;            // 128*129
  int n = blk / 129, p = blk % 129;
  int lane = threadIdx.x;
  int img = ct_img[n];
  float px, py;
  if (p == 0) { int ind = ct_ind[n]; px = (float)(ind % WW); py = (float)(ind / WW); }
  else { px = initp[n * 256 + 2 * (p - 1)]; py = initp[n * 256 + 2 * (p - 1) + 1]; }
  float x = __fsub_rn(px, 0.5f), y = __fsub_rn(py, 0.5f);
  float x0f = floorf(x), y0f = floorf(y);
  float wx = __fsub_rn(x, x0f), wy = __fsub_rn(y, y0f);
  int x0 = (int)x0f, y0 = (int)y0f;
  const float* fb = feat + (size_t)img * CHW + (size_t)lane * HW;
  float g[4];
#pragma unroll
  for (int q = 0; q < 4; ++q) {
    int xi = x0 + (q & 1), yi = y0 + (q >> 1);
    bool valid = (xi >= 0) && (xi < WW) && (yi >= 0) && (yi < HH);
    int xc = min(max(xi, 0), WW - 1), yc = min(max(yi, 0), HH - 1);
    float v = fb[yc * WW + xc];
    g[q] = valid ? v : 0.f;
  }
  float omx = __fsub_rn(1.f, wx), omy = __fsub_rn(1.f, wy);
  float r = __fadd_rn(__fadd_rn(__fadd_rn(
      __fmul_rn(__fmul_rn(g[0], omx), omy),
      __fmul_rn(__fmul_rn(g[1], wx),  omy)),
      __fmul_rn(__fmul_rn(g[2], omx), wy)),
      __fmul_rn(__fmul_rn(g[3], wx),  wy));
  fp[(size_t)n * 8256 + (size_t)lane * 129 + p] = r;
}

// ------------------------------------------------- GEMM1: tmp = fp @ Wp^T ----
// 64x64 tile, 4x4 per thread, k split 16 ways, atomicAdd partials.
__global__ __launch_bounds__(256) void k_gemm1(const float* __restrict__ fp,
    const float* __restrict__ wpoly, float* __restrict__ tmp) {
  int ntile = blockIdx.x;   // 0..1
  int jtile = blockIdx.y;   // 0..7
  int ks    = blockIdx.z;   // 0..15
  int c0 = (129 * ks) / 16, c1 = (129 * (ks + 1)) / 16;
  int t = threadIdx.x;
  int tn = t & 15, tj = t >> 4;
  __shared__ float aS[64][65];
  __shared__ float bS[64][65];
  float acc[4][4];
#pragma unroll
  for (int i = 0; i < 4; ++i)
#pragma unroll
    for (int j = 0; j < 4; ++j) acc[i][j] = 0.f;
  for (int ch = c0; ch < c1; ++ch) {
    int k0 = ch * 64;
    __syncthreads();
    for (int idx = t; idx < 4096; idx += 256) {
      int r = idx >> 6, cc = idx & 63;
      aS[cc][r] = fp[(size_t)(ntile * 64 + r) * 8256 + k0 + cc];
      bS[cc][r] = wpoly[(size_t)(jtile * 64 + r) * 8256 + k0 + cc];
    }
    __syncthreads();
    for (int kk = 0; kk < 64; ++kk) {
      float a0 = aS[kk][tn * 4], a1 = aS[kk][tn * 4 + 1], a2 = aS[kk][tn * 4 + 2], a3 = aS[kk][tn * 4 + 3];
      float b0 = bS[kk][tj * 4], b1 = bS[kk][tj * 4 + 1], b2 = bS[kk][tj * 4 + 2], b3 = bS[kk][tj * 4 + 3];
      acc[0][0] = fmaf(a0, b0, acc[0][0]); acc[0][1] = fmaf(a0, b1, acc[0][1]);
      acc[0][2] = fmaf(a0, b2, acc[0][2]); acc[0][3] = fmaf(a0, b3, acc[0][3]);
      acc[1][0] = fmaf(a1, b0, acc[1][0]); acc[1][1] = fmaf(a1, b1, acc[1][1]);
      acc[1][2] = fmaf(a1, b2, acc[1][2]); acc[1][3] = fmaf(a1, b3, acc[1][3]);
      acc[2][0] = fmaf(a2, b0, acc[2][0]); acc[2][1] = fmaf(a2, b1, acc[2][1]);
      acc[2][2] = fmaf(a2, b2, acc[2][2]); acc[2][3] = fmaf(a2, b3, acc[2][3]);
      acc[3][0] = fmaf(a3, b0, acc[3][0]); acc[3][1] = fmaf(a3, b1, acc[3][1]);
      acc[3][2] = fmaf(a3, b2, acc[3][2]); acc[3][3] = fmaf(a3, b3, acc[3][3]);
    }
  }
#pragma unroll
  for (int i = 0; i < 4; ++i)
#pragma unroll
    for (int j = 0; j < 4; ++j)
      atomicAdd(&tmp[(size_t)(ntile * 64 + tn * 4 + i) * 512 + jtile * 64 + tj * 4 + j], acc[i][j]);
}

// -------------------------------------- GEMM2 + coarse assembly + out1 ----
__global__ __launch_bounds__(256) void k_gemm2(const float* __restrict__ tmp,
    const float* __restrict__ wfT, const float* __restrict__ bfuse,
    const float* __restrict__ initp, float* __restrict__ coarse, float* __restrict__ out1) {
  int n = blockIdx.x, r = threadIdx.x;
  __shared__ float tS[512];
  tS[r] = tmp[n * 512 + r];
  tS[r + 256] = tmp[n * 512 + 256 + r];
  __syncthreads();
  float acc = 0.f;
  for (int j = 0; j < 512; ++j) acc = fmaf(wfT[j * 256 + r], tS[j], acc);
  acc = __fadd_rn(acc, bfuse[r]);
  float cr = __fadd_rn(__fmul_rn(acc, 4.0f), initp[n * 256 + r]);
  coarse[n * 256 + r] = cr;
  out1[n * 256 + r] = __fmul_rn(cr, 4.0f);
}

// -------------------------------------------------------------- final feat ----
__global__ void k_final(float* __restrict__ feat, const float* __restrict__ u) {
  size_t i = (size_t)blockIdx.x * 256 + threadIdx.x;  // 9437184
  int b = (int)(i / ((size_t)CHW));
  int yx = (int)(i % HW);
  float f = feat[i];
  float uu = u[b * HW + yx];
  feat[i] = fmaxf(__fadd_rn(__fmul_rn(uu, f), f), 0.f);
}

extern "C" void kernel_launch(void* const* d_in, const int* in_sizes, int n_in,
                              void* d_out, int out_size, void* d_ws, size_t ws_size,
                              hipStream_t stream) {
  const float* wh    = (const float*)d_in[0];
  const float* cnnf  = (const float*)d_in[1];
  const float* c1w   = (const float*)d_in[2];
  const float* c1b   = (const float*)d_in[3];
  const float* c2w   = (const float*)d_in[4];
  const float* c2b   = (const float*)d_in[5];
  const float* wpoly = (const float*)d_in[6];
  const float* wfuse = (const float*)d_in[7];
  const float* bfuse = (const float*)d_in[8];
  const int* ct_ind  = (const int*)d_in[9];
  const int* ct_img  = (const int*)d_in[10];

  float* ws    = (float*)d_ws;
  float* w2t   = ws;               // 16384
  float* wfT   = w2t + 16384;      // 131072
  float* initp = wfT + 131072;     // 32768
  float* coarse= initp + 32768;    // 32768
  float* tmp   = coarse + 32768;   // 65536
  float* u0    = tmp + 65536;      // 147456
  float* u1    = u0 + 147456;      // 147456
  float* fpbuf = u1 + 147456;      // 1056768  (total ~6.5 MB)

  float* out0 = (float*)d_out;         // init_polys*4   32768
  float* out1 = out0 + 32768;          // coarse*4       32768
  float* out2 = out1 + 32768;          // mb_init        4718592
  float* out3 = out2 + 4718592;        // mb_c           4718592
  float* out4 = out3 + 4718592;        // feat           9437184
  float* feat = out4;                  // feat scratch lives in out4 (fp32)

  k_prep<<<832, 256, 0, stream>>>(c2w, wfuse, w2t, wfT, tmp);
  k_init_polys<<<128, 128, 0, stream>>>(wh, ct_ind, ct_img, initp, out0);
  k_conv<<<dim3(144, 4), 256, 0, stream>>>(cnnf, c1w, c1b, w2t, c2b, feat);
  k_pnp<<<dim3(192, 64), 64, 0, stream>>>(initp, out2);
  k_union<<<576, 256, 0, stream>>>(out2, u0);
  k_maskrelu<<<36864, 256, 0, stream>>>(feat, u0);
  k_sample<<<128 * 129, 64, 0, stream>>>(feat, initp, ct_ind, ct_img, fpbuf);
  k_gemm1<<<dim3(2, 8, 16), 256, 0, stream>>>(fpbuf, wpoly, tmp);
  k_gemm2<<<128, 256, 0, stream>>>(tmp, wfT, bfuse, initp, coarse, out1);
  k_pnp<<<dim3(192, 64), 64, 0, stream>>>(coarse, out3);
  k_union<<<576, 256, 0, stream>>>(out3, u1);
  k_final<<<36864, 256, 0, stream>>>(feat, u1);
}

// Round 3
// 780.351 us; speedup vs baseline: 4.4092x; 4.4092x over previous
//
#include <hip/hip_runtime.h>
#include <hip/hip_bf16.h>

#define HH 192
#define WW 192
#define HW 36864           // 192*192
#define CHW 2359296        // 64*36864

typedef __attribute__((ext_vector_type(8))) short short8;
typedef __attribute__((ext_vector_type(4))) float float4v;

static __device__ __forceinline__ unsigned short f2bu(float f) {
  union { float f; unsigned u; } v; v.f = f;
  unsigned r = (v.u + 0x7fffu + ((v.u >> 16) & 1u)) >> 16;   // RNE bf16
  return (unsigned short)r;
}

// ---------------------------------------------------------------- prep ----
// w1 repack->bf16 [oc][tap*64+ic]; w2->bf16 [c][oc]; wfuse transpose; tmp zero.
__global__ void k_prep(const float* __restrict__ c1w, const float* __restrict__ c2w,
                       const float* __restrict__ wfuse,
                       unsigned short* __restrict__ w1b, unsigned short* __restrict__ w2b,
                       float* __restrict__ wfT, float* __restrict__ tmp) {
  int i = blockIdx.x * 256 + threadIdx.x;
  if (i < 147456) {
    int oc = i / 576, r = i % 576;
    int tap = r >> 6, ic = r & 63;
    int ky = tap / 3, kx = tap % 3;
    w1b[i] = f2bu(c1w[((oc * 64 + ic) * 3 + ky) * 3 + kx]);
    return;
  }
  int j = i - 147456;
  if (j < 16384) { w2b[j] = f2bu(c2w[j]); return; }   // c2w is [c][oc] already
  int k = j - 16384;
  if (k < 131072) { int jj = k >> 8, r = k & 255; wfT[k] = wfuse[r * 512 + jj]; return; }
  int z = k - 131072;
  if (z >= 0 && z < 65536) tmp[z] = 0.f;
}

// ---------------------------------------------------- init polys + out0 ----
__global__ void k_init_polys(const float* __restrict__ wh, const int* __restrict__ ct_ind,
                             const int* __restrict__ ct_img,
                             float* __restrict__ initp, float* __restrict__ out0) {
  int n = blockIdx.x;     // 0..127
  int p = threadIdx.x;    // 0..127
  int ind = ct_ind[n], img = ct_img[n];
  int cx = ind % WW, cy = ind / WW;
  size_t base = ((size_t)(img * 256 + 2 * p)) * HW + (size_t)cy * WW + cx;
  float ox = wh[base];
  float oy = wh[base + HW];
  float px = __fadd_rn(__fmul_rn(ox, 10.0f), (float)cx);
  float py = __fadd_rn(__fmul_rn(oy, 10.0f), (float)cy);
  initp[n * 256 + 2 * p]     = px;
  initp[n * 256 + 2 * p + 1] = py;
  out0[n * 256 + 2 * p]      = __fmul_rn(px, 4.0f);
  out0[n * 256 + 2 * p + 1]  = __fmul_rn(py, 4.0f);
}

// ------------------------------------------- fused conv1+relu+conv2+gate ----
// bf16 MFMA implicit GEMM. Block = 4 waves = 64-px row segment.
// conv1: M=64 px, N=256 oc (4 groups), K=576 (tap*64+ic). A-frags register-
// resident (18 x b128); B from L2-hot global dwordx4. y1 relu'd -> LDS bf16
// (reusing x-stage buffer), conv2: K=256 accumulated over ocgroups.
// Epilogue fuses feat = relu(u0*f + f).
__global__ __launch_bounds__(256) void k_conv(const float* __restrict__ x,
    const unsigned short* __restrict__ w1b, const float* __restrict__ b1,
    const unsigned short* __restrict__ w2b, const float* __restrict__ b2,
    const float* __restrict__ u0, float* __restrict__ feat) {
  int blk = blockIdx.x;            // 4*192*3
  int b   = blk / 576;
  int rem = blk % 576;
  int y   = rem / 3;
  int x0  = (rem % 3) * 64;
  int t = threadIdx.x;
  int w = t >> 6, l = t & 63;
  int m = l & 15, q = l >> 4;
  __shared__ __align__(16) unsigned short sb[3 * 66 * 72];   // xS, then y1S

  // stage x halo (3 rows x 66 px x 64 ic) fp32->bf16, layout [row][x][ic(+pad 72)]
  for (int idx = t; idx < 3 * 64 * 66; idx += 256) {
    int r = idx / (64 * 66); int r2 = idx % (64 * 66);
    int ic = r2 / 66; int xx = r2 % 66;
    int gy = y + r - 1, gx = x0 + xx - 1;
    float v = 0.f;
    if (gy >= 0 && gy < HH && gx >= 0 && gx < WW)
      v = x[(size_t)(b * 64 + ic) * HW + (size_t)gy * WW + gx];
    sb[(r * 66 + xx) * 72 + ic] = f2bu(v);
  }
  __syncthreads();

  // A-fragments: aF[s], s = K-step; k = s*32 + q*8 + j; tap=s>>1, ic0=(s&1)*32+q*8
  short8 aF[18];
#pragma unroll
  for (int s = 0; s < 18; ++s) {
    int tap = s >> 1; int ky = tap / 3, kx = tap % 3;
    int ic0 = (s & 1) * 32 + q * 8;
    int px = w * 16 + m;
    aF[s] = *(const short8*)&sb[(ky * 66 + px + kx) * 72 + ic0];
  }

  float4v facc[4];
#pragma unroll
  for (int nt = 0; nt < 4; ++nt) {
    float bias = b2[nt * 16 + m];
    facc[nt] = (float4v){bias, bias, bias, bias};
  }

  for (int ocg = 0; ocg < 4; ++ocg) {
    float4v yacc[4];
#pragma unroll
    for (int nt = 0; nt < 4; ++nt) {
      float bias = b1[ocg * 64 + nt * 16 + m];
      yacc[nt] = (float4v){bias, bias, bias, bias};
    }
#pragma unroll
    for (int s = 0; s < 18; ++s) {
#pragma unroll
      for (int nt = 0; nt < 4; ++nt) {
        int oc = ocg * 64 + nt * 16 + m;
        short8 bF = *(const short8*)&w1b[(size_t)oc * 576 + s * 32 + q * 8];
        yacc[nt] = __builtin_amdgcn_mfma_f32_16x16x32_bf16(aF[s], bF, yacc[nt], 0, 0, 0);
      }
    }
    // y1 -> LDS (bf16, relu). Barrier guards: (a) ocg0: xS reads (aF) done by
    // all waves; (b) ocg>0: previous conv2 reads of sb done.
    __syncthreads();
#pragma unroll
    for (int nt = 0; nt < 4; ++nt)
#pragma unroll
      for (int r = 0; r < 4; ++r) {
        int px = w * 16 + q * 4 + r;                 // C/D: row=(l>>4)*4+reg
        sb[px * 72 + nt * 16 + m] = f2bu(fmaxf(yacc[nt][r], 0.f));  // col=l&15
      }
    __syncthreads();
    // conv2: feat(64px x 64c) += y1(64px x 64oc) @ w2[c][oc]
#pragma unroll
    for (int s2 = 0; s2 < 2; ++s2) {
      int px = w * 16 + m;
      short8 a2 = *(const short8*)&sb[px * 72 + s2 * 32 + q * 8];
#pragma unroll
      for (int nt = 0; nt < 4; ++nt) {
        int c = nt * 16 + m;
        short8 bF2 = *(const short8*)&w2b[(size_t)c * 256 + ocg * 64 + s2 * 32 + q * 8];
        facc[nt] = __builtin_amdgcn_mfma_f32_16x16x32_bf16(a2, bF2, facc[nt], 0, 0, 0);
      }
    }
  }

  // epilogue: feat = relu(u0*f + f)  (fused mask-gate)
#pragma unroll
  for (int nt = 0; nt < 4; ++nt)
#pragma unroll
    for (int r = 0; r < 4; ++r) {
      int px = x0 + w * 16 + q * 4 + r;
      int c = nt * 16 + m;
      float f = facc[nt][r];
      float uu = u0[b * HW + y * WW + px];
      feat[(size_t)b * CHW + (size_t)c * HW + (size_t)y * WW + px] = fmaxf(uu * f + f, 0.f);
    }
}

// ------------------------------------------------------ point-in-polygon ----
// one wave per (row, poly). Only polys 0..63 ever used (_mask_batch slicing
// bug replicated: batches 1,2,3 all get polys 32..63).
__global__ __launch_bounds__(64) void k_pnp(const float* __restrict__ polys,
                                            float* __restrict__ outm) {
  int row  = blockIdx.x;   // 0..191
  int n    = blockIdx.y;   // 0..63
  int lane = threadIdx.x;
  __shared__ float vx[128], vy[128], xint[128];
  __shared__ int cnt;
  if (lane == 0) cnt = 0;
  vx[lane]      = polys[n * 256 + 2 * lane];
  vy[lane]      = polys[n * 256 + 2 * lane + 1];
  vx[lane + 64] = polys[n * 256 + 2 * (lane + 64)];
  vy[lane + 64] = polys[n * 256 + 2 * (lane + 64) + 1];
  __syncthreads();
  float yy = (float)row;
  for (int e = lane; e < 128; e += 64) {
    float y1 = vy[e], y2 = vy[(e + 1) & 127];
    if ((y1 > yy) != (y2 > yy)) {
      float x1 = vx[e], x2 = vx[(e + 1) & 127];
      float den = __fsub_rn(y2, y1);
      if (fabsf(den) < 1e-9f) den = 1e-9f;
      float xi = __fadd_rn(x1, __fdiv_rn(__fmul_rn(__fsub_rn(x2, x1), __fsub_rn(yy, y1)), den));
      xint[atomicAdd(&cnt, 1)] = xi;
    }
  }
  __syncthreads();
  int mm = cnt;
  int bb = (n < 32) ? 0 : 1;
  int cc = n & 31;
  size_t base = ((size_t)(bb * 32 + cc) * HH + row) * WW;
  for (int xp = lane; xp < WW; xp += 64) {
    float xf = (float)xp;
    int c = 0;
    for (int j = 0; j < mm; ++j) c += (xf < xint[j]) ? 1 : 0;
    float mv = (float)(c & 1);
    outm[base + xp] = mv;
    if (n >= 32) {
      outm[base + (size_t)32 * HW + xp] = mv;
      outm[base + (size_t)64 * HW + xp] = mv;
    }
  }
}

// ------------------------------------------------------------ union mask ----
__global__ void k_union(const float* __restrict__ m, float* __restrict__ u) {
  int i = blockIdx.x * 256 + threadIdx.x;   // 4*HW
  if (i >= 4 * HW) return;
  int b = i / HW, yx = i - b * HW;
  const float* p = m + (size_t)b * 32 * HW + yx;
  float mx = 0.f;
  for (int c = 0; c < 32; ++c) mx = fmaxf(mx, p[(size_t)c * HW]);
  u[i] = mx;
}

// ------------------------------------------------------- bilinear sample ----
__global__ __launch_bounds__(64) void k_sample(const float* __restrict__ feat,
    const float* __restrict__ initp, const int* __restrict__ ct_ind,
    const int* __restrict__ ct_img, float* __restrict__ fp) {
  int blk = blockIdx.x;            // 128*129
  int n = blk / 129, p = blk % 129;
  int lane = threadIdx.x;
  int img = ct_img[n];
  float px, py;
  if (p == 0) { int ind = ct_ind[n]; px = (float)(ind % WW); py = (float)(ind / WW); }
  else { px = initp[n * 256 + 2 * (p - 1)]; py = initp[n * 256 + 2 * (p - 1) + 1]; }
  float x = __fsub_rn(px, 0.5f), y = __fsub_rn(py, 0.5f);
  float x0f = floorf(x), y0f = floorf(y);
  float wx = __fsub_rn(x, x0f), wy = __fsub_rn(y, y0f);
  int x0 = (int)x0f, y0 = (int)y0f;
  const float* fb = feat + (size_t)img * CHW + (size_t)lane * HW;
  float g[4];
#pragma unroll
  for (int qq = 0; qq < 4; ++qq) {
    int xi = x0 + (qq & 1), yi = y0 + (qq >> 1);
    bool valid = (xi >= 0) && (xi < WW) && (yi >= 0) && (yi < HH);
    int xc = min(max(xi, 0), WW - 1), yc = min(max(yi, 0), HH - 1);
    float v = fb[yc * WW + xc];
    g[qq] = valid ? v : 0.f;
  }
  float omx = __fsub_rn(1.f, wx), omy = __fsub_rn(1.f, wy);
  float r = __fadd_rn(__fadd_rn(__fadd_rn(
      __fmul_rn(__fmul_rn(g[0], omx), omy),
      __fmul_rn(__fmul_rn(g[1], wx),  omy)),
      __fmul_rn(__fmul_rn(g[2], omx), wy)),
      __fmul_rn(__fmul_rn(g[3], wx),  wy));
  fp[(size_t)n * 8256 + (size_t)lane * 129 + p] = r;
}

// ------------------------------------------------- GEMM1: tmp = fp @ Wp^T ----
__global__ __launch_bounds__(256) void k_gemm1(const float* __restrict__ fp,
    const float* __restrict__ wpoly, float* __restrict__ tmp) {
  int ntile = blockIdx.x;   // 0..1
  int jtile = blockIdx.y;   // 0..7
  int ks    = blockIdx.z;   // 0..15
  int c0 = (129 * ks) / 16, c1 = (129 * (ks + 1)) / 16;
  int t = threadIdx.x;
  int tn = t & 15, tj = t >> 4;
  __shared__ float aS[64][65];
  __shared__ float bS[64][65];
  float acc[4][4];
#pragma unroll
  for (int i = 0; i < 4; ++i)
#pragma unroll
    for (int j = 0; j < 4; ++j) acc[i][j] = 0.f;
  for (int ch = c0; ch < c1; ++ch) {
    int k0 = ch * 64;
    __syncthreads();
    for (int idx = t; idx < 4096; idx += 256) {
      int r = idx >> 6, cc = idx & 63;
      aS[cc][r] = fp[(size_t)(ntile * 64 + r) * 8256 + k0 + cc];
      bS[cc][r] = wpoly[(size_t)(jtile * 64 + r) * 8256 + k0 + cc];
    }
    __syncthreads();
    for (int kk = 0; kk < 64; ++kk) {
      float a0 = aS[kk][tn * 4], a1 = aS[kk][tn * 4 + 1], a2 = aS[kk][tn * 4 + 2], a3 = aS[kk][tn * 4 + 3];
      float b0 = bS[kk][tj * 4], b1 = bS[kk][tj * 4 + 1], b2 = bS[kk][tj * 4 + 2], b3 = bS[kk][tj * 4 + 3];
      acc[0][0] = fmaf(a0, b0, acc[0][0]); acc[0][1] = fmaf(a0, b1, acc[0][1]);
      acc[0][2] = fmaf(a0, b2, acc[0][2]); acc[0][3] = fmaf(a0, b3, acc[0][3]);
      acc[1][0] = fmaf(a1, b0, acc[1][0]); acc[1][1] = fmaf(a1, b1, acc[1][1]);
      acc[1][2] = fmaf(a1, b2, acc[1][2]); acc[1][3] = fmaf(a1, b3, acc[1][3]);
      acc[2][0] = fmaf(a2, b0, acc[2][0]); acc[2][1] = fmaf(a2, b1, acc[2][1]);
      acc[2][2] = fmaf(a2, b2, acc[2][2]); acc[2][3] = fmaf(a2, b3, acc[2][3]);
      acc[3][0] = fmaf(a3, b0, acc[3][0]); acc[3][1] = fmaf(a3, b1, acc[3][1]);
      acc[3][2] = fmaf(a3, b2, acc[3][2]); acc[3][3] = fmaf(a3, b3, acc[3][3]);
    }
  }
#pragma unroll
  for (int i = 0; i < 4; ++i)
#pragma unroll
    for (int j = 0; j < 4; ++j)
      atomicAdd(&tmp[(size_t)(ntile * 64 + tn * 4 + i) * 512 + jtile * 64 + tj * 4 + j], acc[i][j]);
}

// -------------------------------------- GEMM2 + coarse assembly + out1 ----
__global__ __launch_bounds__(256) void k_gemm2(const float* __restrict__ tmp,
    const float* __restrict__ wfT, const float* __restrict__ bfuse,
    const float* __restrict__ initp, float* __restrict__ coarse, float* __restrict__ out1) {
  int n = blockIdx.x, r = threadIdx.x;
  __shared__ float tS[512];
  tS[r] = tmp[n * 512 + r];
  tS[r + 256] = tmp[n * 512 + 256 + r];
  __syncthreads();
  float acc = 0.f;
  for (int j = 0; j < 512; ++j) acc = fmaf(wfT[j * 256 + r], tS[j], acc);
  acc = __fadd_rn(acc, bfuse[r]);
  float cr = __fadd_rn(__fmul_rn(acc, 4.0f), initp[n * 256 + r]);
  coarse[n * 256 + r] = cr;
  out1[n * 256 + r] = __fmul_rn(cr, 4.0f);
}

// -------------------------------------------------------------- final feat ----
__global__ void k_final(float* __restrict__ feat, const float* __restrict__ u) {
  size_t i = (size_t)blockIdx.x * 256 + threadIdx.x;  // 9437184
  int b = (int)(i / ((size_t)CHW));
  int yx = (int)(i % HW);
  float f = feat[i];
  float uu = u[b * HW + yx];
  feat[i] = fmaxf(__fadd_rn(__fmul_rn(uu, f), f), 0.f);
}

extern "C" void kernel_launch(void* const* d_in, const int* in_sizes, int n_in,
                              void* d_out, int out_size, void* d_ws, size_t ws_size,
                              hipStream_t stream) {
  const float* wh    = (const float*)d_in[0];
  const float* cnnf  = (const float*)d_in[1];
  const float* c1w   = (const float*)d_in[2];
  const float* c1b   = (const float*)d_in[3];
  const float* c2w   = (const float*)d_in[4];
  const float* c2b   = (const float*)d_in[5];
  const float* wpoly = (const float*)d_in[6];
  const float* wfuse = (const float*)d_in[7];
  const float* bfuse = (const float*)d_in[8];
  const int* ct_ind  = (const int*)d_in[9];
  const int* ct_img  = (const int*)d_in[10];

  float* ws    = (float*)d_ws;
  float* wfT   = ws;               // 131072 fp32
  float* initp = wfT + 131072;     // 32768
  float* coarse= initp + 32768;    // 32768
  float* tmp   = coarse + 32768;   // 65536
  float* u0    = tmp + 65536;      // 147456
  float* u1    = u0 + 147456;      // 147456
  float* fpbuf = u1 + 147456;      // 1056768
  unsigned short* w1b = (unsigned short*)(fpbuf + 1056768);  // 147456 bf16
  unsigned short* w2b = w1b + 147456;                        // 16384 bf16
  // total ~6.6 MB

  float* out0 = (float*)d_out;         // init_polys*4   32768
  float* out1 = out0 + 32768;          // coarse*4       32768
  float* out2 = out1 + 32768;          // mb_init        4718592
  float* out3 = out2 + 4718592;        // mb_c           4718592
  float* out4 = out3 + 4718592;        // feat           9437184
  float* feat = out4;                  // feat scratch lives in out4 (fp32)

  k_prep<<<1408, 256, 0, stream>>>(c1w, c2w, wfuse, w1b, w2b, wfT, tmp);
  k_init_polys<<<128, 128, 0, stream>>>(wh, ct_ind, ct_img, initp, out0);
  k_pnp<<<dim3(192, 64), 64, 0, stream>>>(initp, out2);
  k_union<<<576, 256, 0, stream>>>(out2, u0);
  k_conv<<<4 * 192 * 3, 256, 0, stream>>>(cnnf, w1b, c1b, w2b, c2b, u0, feat);
  k_sample<<<128 * 129, 64, 0, stream>>>(feat, initp, ct_ind, ct_img, fpbuf);
  k_gemm1<<<dim3(2, 8, 16), 256, 0, stream>>>(fpbuf, wpoly, tmp);
  k_gemm2<<<128, 256, 0, stream>>>(tmp, wfT, bfuse, initp, coarse, out1);
  k_pnp<<<dim3(192, 64), 64, 0, stream>>>(coarse, out3);
  k_union<<<576, 256, 0, stream>>>(out3, u1);
  k_final<<<36864, 256, 0, stream>>>(feat, u1);
}

// Round 4
// 532.172 us; speedup vs baseline: 6.4654x; 1.4664x over previous
//
#include <hip/hip_runtime.h>
#include <hip/hip_bf16.h>

#define HH 192
#define WW 192
#define HW 36864           // 192*192
#define CHW 2359296        // 64*36864

typedef __attribute__((ext_vector_type(8))) short short8;
typedef __attribute__((ext_vector_type(4))) float float4v;

static __device__ __forceinline__ unsigned short f2bu(float f) {
  union { float f; unsigned u; } v; v.f = f;
  unsigned r = (v.u + 0x7fffu + ((v.u >> 16) & 1u)) >> 16;   // RNE bf16
  return (unsigned short)r;
}

// ---------------------------------------------------------------- prep ----
// wB1/wB2: weights repacked into MFMA B-fragment-linear order so each
// B-frag load in k_conv is one contiguous 1KiB coalesced wave load.
// wB1[(T*18+s)*512 + l*8 + j] = w1[oc=T*16+m][k=s*32+q*8+j], k=tap*64+ic.
// Also wfuse transpose, tmp zero, u0/u1 zero.
__global__ void k_prep(const float* __restrict__ c1w, const float* __restrict__ c2w,
                       const float* __restrict__ wfuse,
                       unsigned short* __restrict__ wB1, unsigned short* __restrict__ wB2,
                       float* __restrict__ wfT, float* __restrict__ tmp,
                       float* __restrict__ u01) {
  int i = blockIdx.x * 256 + threadIdx.x;
  if (i < 147456) {
    int T = i / 9216, r = i % 9216;
    int s = r / 512, e = r % 512;
    int l = e >> 3, j = e & 7;
    int m = l & 15, q = l >> 4;
    int oc = T * 16 + m;
    int k = s * 32 + q * 8 + j;
    int tap = k >> 6, ic = k & 63;
    int ky = tap / 3, kx = tap % 3;
    wB1[i] = f2bu(c1w[((oc * 64 + ic) * 3 + ky) * 3 + kx]);
    return;
  }
  int j2 = i - 147456;
  if (j2 < 16384) {
    int g = j2 / 512, e = j2 % 512;
    int l = e >> 3, jj = e & 7;
    int m = l & 15, q = l >> 4;
    int w = g / 8, s2 = g % 8;
    wB2[j2] = f2bu(c2w[(w * 16 + m) * 256 + s2 * 32 + q * 8 + jj]);
    return;
  }
  int k3 = j2 - 16384;
  if (k3 < 131072) { int jj = k3 >> 8, r = k3 & 255; wfT[k3] = wfuse[r * 512 + jj]; return; }
  int z = k3 - 131072;
  if (z < 65536) { tmp[z] = 0.f; return; }
  int v = z - 65536;
  if (v < 294912) u01[v] = 0.f;     // u0 then u1 (contiguous in ws)
}

// ---------------------------------------------------- init polys + out0 ----
__global__ void k_init_polys(const float* __restrict__ wh, const int* __restrict__ ct_ind,
                             const int* __restrict__ ct_img,
                             float* __restrict__ initp, float* __restrict__ out0) {
  int n = blockIdx.x;     // 0..127
  int p = threadIdx.x;    // 0..127
  int ind = ct_ind[n], img = ct_img[n];
  int cx = ind % WW, cy = ind / WW;
  size_t base = ((size_t)(img * 256 + 2 * p)) * HW + (size_t)cy * WW + cx;
  float ox = wh[base];
  float oy = wh[base + HW];
  float px = __fadd_rn(__fmul_rn(ox, 10.0f), (float)cx);
  float py = __fadd_rn(__fmul_rn(oy, 10.0f), (float)cy);
  initp[n * 256 + 2 * p]     = px;
  initp[n * 256 + 2 * p + 1] = py;
  out0[n * 256 + 2 * p]      = __fmul_rn(px, 4.0f);
  out0[n * 256 + 2 * p + 1]  = __fmul_rn(py, 4.0f);
}

// ------------------------------------------- fused conv1+relu+conv2+gate ----
// Register-tiled implicit GEMM. Block = 4 waves, tile M=128 px (2 rows x 64),
// N=256 oc. Wave w owns oc-quad: acc 8x4 16x16 tiles (128 VGPRs).
// Per K-step: 8 ds_read_b128 A-frags + 4 coalesced B-frag loads -> 32 MFMAs.
// y1 relu'd -> LDS bf16 (union with x-stage), conv2 K=256 (8 steps),
// epilogue: LDS transpose -> coalesced feat stores with fused u0 gate.
__global__ __launch_bounds__(256, 2) void k_conv(const float* __restrict__ x,
    const unsigned short* __restrict__ wB1, const float* __restrict__ b1,
    const unsigned short* __restrict__ wB2, const float* __restrict__ b2,
    const float* __restrict__ u0, float* __restrict__ feat) {
  int blk = blockIdx.x;            // 4 * 96 * 3
  int b    = blk / 288;
  int rem  = blk % 288;
  int pair = rem / 3;
  int xs   = rem % 3;
  int y0 = pair * 2, x0 = xs * 64;
  int t = threadIdx.x;
  int w = t >> 6, l = t & 63;
  int m = l & 15, q = l >> 4;

  __shared__ __align__(16) unsigned short sb[33792];   // 67.5 KB union buffer

  // ---- stage x halo: 4 rows x 66 px x 64 ic -> bf16 [(row*66+xx)*72 + ic]
  for (int it = 0; it < 66; ++it) {
    int idx = it * 256 + t;          // 0..16895
    int r  = idx / 4224;             // 66*64
    int r2 = idx - r * 4224;
    int ic = r2 / 66;
    int xx = r2 - ic * 66;
    int gy = y0 + r - 1, gx = x0 + xx - 1;
    float v = 0.f;
    if (gy >= 0 && gy < HH && gx >= 0 && gx < WW)
      v = x[(size_t)(b * 64 + ic) * HW + (size_t)gy * WW + gx];
    sb[(r * 66 + xx) * 72 + ic] = f2bu(v);
  }
  __syncthreads();

  // ---- conv1: M=128, N=64 (this wave), K=576
  float4v acc1[8][4];
#pragma unroll
  for (int nt = 0; nt < 4; ++nt) {
    float bv = b1[w * 64 + nt * 16 + m];
#pragma unroll
    for (int mt = 0; mt < 8; ++mt) acc1[mt][nt] = (float4v){bv, bv, bv, bv};
  }

#pragma unroll
  for (int s = 0; s < 18; ++s) {
    int tap = s >> 1, ky = tap / 3, kx = tap - ky * 3;
    int ic0 = (s & 1) * 32 + q * 8;
    short8 bF[4];
#pragma unroll
    for (int nt = 0; nt < 4; ++nt)
      bF[nt] = *(const short8*)&wB1[(size_t)((((w * 4 + nt) * 18 + s) * 512) + l * 8)];
    short8 aF[8];
#pragma unroll
    for (int mt = 0; mt < 8; ++mt) {
      int col  = (mt & 3) * 16 + m + kx;
      int rowi = ky + (mt >> 2);
      aF[mt] = *(const short8*)&sb[(rowi * 66 + col) * 72 + ic0];
    }
#pragma unroll
    for (int nt = 0; nt < 4; ++nt)
#pragma unroll
      for (int mt = 0; mt < 8; ++mt)
        acc1[mt][nt] = __builtin_amdgcn_mfma_f32_16x16x32_bf16(aF[mt], bF[nt], acc1[mt][nt], 0, 0, 0);
  }
  __syncthreads();                       // all xS reads done

  // ---- y1 (relu, bf16) -> LDS [px*264 + oc]
#pragma unroll
  for (int mt = 0; mt < 8; ++mt)
#pragma unroll
    for (int nt = 0; nt < 4; ++nt)
#pragma unroll
      for (int r = 0; r < 4; ++r) {
        int p = mt * 16 + q * 4 + r;           // C/D: row = q*4+reg (M=px)
        int oc = w * 64 + nt * 16 + m;         // col = lane&15 (N=oc)
        sb[p * 264 + oc] = f2bu(fmaxf(acc1[mt][nt][r], 0.f));
      }
  __syncthreads();

  // ---- conv2: M=128, N=16 (this wave), K=256
  float4v acc2[8];
  {
    float bv = b2[w * 16 + m];
#pragma unroll
    for (int mt = 0; mt < 8; ++mt) acc2[mt] = (float4v){bv, bv, bv, bv};
  }
#pragma unroll
  for (int s2 = 0; s2 < 8; ++s2) {
    short8 bF2 = *(const short8*)&wB2[(size_t)(((w * 8 + s2) * 512) + l * 8)];
#pragma unroll
    for (int mt = 0; mt < 8; ++mt) {
      short8 a2 = *(const short8*)&sb[(mt * 16 + m) * 264 + s2 * 32 + q * 8];
      acc2[mt] = __builtin_amdgcn_mfma_f32_16x16x32_bf16(a2, bF2, acc2[mt], 0, 0, 0);
    }
  }
  __syncthreads();                       // y1S reads done before overwrite

  // ---- epilogue: transpose via LDS, coalesced store with u0 gate
  float* fS = (float*)sb;                // per-wave 16c x 128px (pad 132)
#pragma unroll
  for (int mt = 0; mt < 8; ++mt)
#pragma unroll
    for (int r = 0; r < 4; ++r) {
      int p = mt * 16 + q * 4 + r;
      fS[w * 2112 + m * 132 + p] = acc2[mt][r];
    }
  const float* ub = u0 + b * HW;
#pragma unroll
  for (int i = 0; i < 32; ++i) {
    int idx = i * 64 + l;
    int c16 = idx >> 7, p = idx & 127;
    float f = fS[w * 2112 + c16 * 132 + p];
    int gy = y0 + (p >> 6), gx = x0 + (p & 63);
    float uu = ub[gy * WW + gx];
    feat[(size_t)(b * 64 + w * 16 + c16) * HW + (size_t)gy * WW + gx] = fmaxf(uu * f + f, 0.f);
  }
}

// ------------------------------------------------------ point-in-polygon ----
// one wave per (row, poly); fused union via atomicOr into u (0/1 as float
// bit pattern). Only polys 0..63 ever used (_mask_batch slicing bug
// replicated: batches 1,2,3 all get polys 32..63).
__global__ __launch_bounds__(64) void k_pnp(const float* __restrict__ polys,
                                            float* __restrict__ outm,
                                            float* __restrict__ u) {
  int row  = blockIdx.x;   // 0..191
  int n    = blockIdx.y;   // 0..63
  int lane = threadIdx.x;
  __shared__ float vx[128], vy[128], xint[128];
  __shared__ int cnt;
  if (lane == 0) cnt = 0;
  vx[lane]      = polys[n * 256 + 2 * lane];
  vy[lane]      = polys[n * 256 + 2 * lane + 1];
  vx[lane + 64] = polys[n * 256 + 2 * (lane + 64)];
  vy[lane + 64] = polys[n * 256 + 2 * (lane + 64) + 1];
  __syncthreads();
  float yy = (float)row;
  for (int e = lane; e < 128; e += 64) {
    float y1 = vy[e], y2 = vy[(e + 1) & 127];
    if ((y1 > yy) != (y2 > yy)) {
      float x1 = vx[e], x2 = vx[(e + 1) & 127];
      float den = __fsub_rn(y2, y1);
      if (fabsf(den) < 1e-9f) den = 1e-9f;
      float xi = __fadd_rn(x1, __fdiv_rn(__fmul_rn(__fsub_rn(x2, x1), __fsub_rn(yy, y1)), den));
      xint[atomicAdd(&cnt, 1)] = xi;
    }
  }
  __syncthreads();
  int mm = cnt;
  int bb = (n < 32) ? 0 : 1;
  int cc = n & 31;
  size_t base = ((size_t)(bb * 32 + cc) * HH + row) * WW;
  for (int xp = lane; xp < WW; xp += 64) {
    float xf = (float)xp;
    int c = 0;
    for (int j = 0; j < mm; ++j) c += (xf < xint[j]) ? 1 : 0;
    float mv = (float)(c & 1);
    outm[base + xp] = mv;
    if (n >= 32) {
      outm[base + (size_t)32 * HW + xp] = mv;
      outm[base + (size_t)64 * HW + xp] = mv;
    }
    if (c & 1) {
      int off = bb * HW + row * WW + xp;
      atomicOr((int*)(u + off), 0x3f800000);
      if (n >= 32) {
        atomicOr((int*)(u + off + HW), 0x3f800000);
        atomicOr((int*)(u + off + 2 * HW), 0x3f800000);
      }
    }
  }
}

// ------------------------------------------------------- bilinear sample ----
__global__ __launch_bounds__(64) void k_sample(const float* __restrict__ feat,
    const float* __restrict__ initp, const int* __restrict__ ct_ind,
    const int* __restrict__ ct_img, float* __restrict__ fp) {
  int blk = blockIdx.x;            // 128*129
  int n = blk / 129, p = blk % 129;
  int lane = threadIdx.x;
  int img = ct_img[n];
  float px, py;
  if (p == 0) { int ind = ct_ind[n]; px = (float)(ind % WW); py = (float)(ind / WW); }
  else { px = initp[n * 256 + 2 * (p - 1)]; py = initp[n * 256 + 2 * (p - 1) + 1]; }
  float x = __fsub_rn(px, 0.5f), y = __fsub_rn(py, 0.5f);
  float x0f = floorf(x), y0f = floorf(y);
  float wx = __fsub_rn(x, x0f), wy = __fsub_rn(y, y0f);
  int x0 = (int)x0f, y0 = (int)y0f;
  const float* fb = feat + (size_t)img * CHW + (size_t)lane * HW;
  float g[4];
#pragma unroll
  for (int qq = 0; qq < 4; ++qq) {
    int xi = x0 + (qq & 1), yi = y0 + (qq >> 1);
    bool valid = (xi >= 0) && (xi < WW) && (yi >= 0) && (yi < HH);
    int xc = min(max(xi, 0), WW - 1), yc = min(max(yi, 0), HH - 1);
    float v = fb[yc * WW + xc];
    g[qq] = valid ? v : 0.f;
  }
  float omx = __fsub_rn(1.f, wx), omy = __fsub_rn(1.f, wy);
  float r = __fadd_rn(__fadd_rn(__fadd_rn(
      __fmul_rn(__fmul_rn(g[0], omx), omy),
      __fmul_rn(__fmul_rn(g[1], wx),  omy)),
      __fmul_rn(__fmul_rn(g[2], omx), wy)),
      __fmul_rn(__fmul_rn(g[3], wx),  wy));
  fp[(size_t)n * 8256 + (size_t)lane * 129 + p] = r;
}

// ------------------------------------------------- GEMM1: tmp = fp @ Wp^T ----
__global__ __launch_bounds__(256) void k_gemm1(const float* __restrict__ fp,
    const float* __restrict__ wpoly, float* __restrict__ tmp) {
  int ntile = blockIdx.x;   // 0..1
  int jtile = blockIdx.y;   // 0..7
  int ks    = blockIdx.z;   // 0..15
  int c0 = (129 * ks) / 16, c1 = (129 * (ks + 1)) / 16;
  int t = threadIdx.x;
  int tn = t & 15, tj = t >> 4;
  __shared__ float aS[64][65];
  __shared__ float bS[64][65];
  float acc[4][4];
#pragma unroll
  for (int i = 0; i < 4; ++i)
#pragma unroll
    for (int j = 0; j < 4; ++j) acc[i][j] = 0.f;
  for (int ch = c0; ch < c1; ++ch) {
    int k0 = ch * 64;
    __syncthreads();
    for (int idx = t; idx < 4096; idx += 256) {
      int r = idx >> 6, cc = idx & 63;
      aS[cc][r] = fp[(size_t)(ntile * 64 + r) * 8256 + k0 + cc];
      bS[cc][r] = wpoly[(size_t)(jtile * 64 + r) * 8256 + k0 + cc];
    }
    __syncthreads();
    for (int kk = 0; kk < 64; ++kk) {
      float a0 = aS[kk][tn * 4], a1 = aS[kk][tn * 4 + 1], a2 = aS[kk][tn * 4 + 2], a3 = aS[kk][tn * 4 + 3];
      float b0 = bS[kk][tj * 4], b1 = bS[kk][tj * 4 + 1], b2 = bS[kk][tj * 4 + 2], b3 = bS[kk][tj * 4 + 3];
      acc[0][0] = fmaf(a0, b0, acc[0][0]); acc[0][1] = fmaf(a0, b1, acc[0][1]);
      acc[0][2] = fmaf(a0, b2, acc[0][2]); acc[0][3] = fmaf(a0, b3, acc[0][3]);
      acc[1][0] = fmaf(a1, b0, acc[1][0]); acc[1][1] = fmaf(a1, b1, acc[1][1]);
      acc[1][2] = fmaf(a1, b2, acc[1][2]); acc[1][3] = fmaf(a1, b3, acc[1][3]);
      acc[2][0] = fmaf(a2, b0, acc[2][0]); acc[2][1] = fmaf(a2, b1, acc[2][1]);
      acc[2][2] = fmaf(a2, b2, acc[2][2]); acc[2][3] = fmaf(a2, b3, acc[2][3]);
      acc[3][0] = fmaf(a3, b0, acc[3][0]); acc[3][1] = fmaf(a3, b1, acc[3][1]);
      acc[3][2] = fmaf(a3, b2, acc[3][2]); acc[3][3] = fmaf(a3, b3, acc[3][3]);
    }
  }
#pragma unroll
  for (int i = 0; i < 4; ++i)
#pragma unroll
    for (int j = 0; j < 4; ++j)
      atomicAdd(&tmp[(size_t)(ntile * 64 + tn * 4 + i) * 512 + jtile * 64 + tj * 4 + j], acc[i][j]);
}

// -------------------------------------- GEMM2 + coarse assembly + out1 ----
__global__ __launch_bounds__(256) void k_gemm2(const float* __restrict__ tmp,
    const float* __restrict__ wfT, const float* __restrict__ bfuse,
    const float* __restrict__ initp, float* __restrict__ coarse, float* __restrict__ out1) {
  int n = blockIdx.x, r = threadIdx.x;
  __shared__ float tS[512];
  tS[r] = tmp[n * 512 + r];
  tS[r + 256] = tmp[n * 512 + 256 + r];
  __syncthreads();
  float acc = 0.f;
  for (int j = 0; j < 512; ++j) acc = fmaf(wfT[j * 256 + r], tS[j], acc);
  acc = __fadd_rn(acc, bfuse[r]);
  float cr = __fadd_rn(__fmul_rn(acc, 4.0f), initp[n * 256 + r]);
  coarse[n * 256 + r] = cr;
  out1[n * 256 + r] = __fmul_rn(cr, 4.0f);
}

// -------------------------------------------------------------- final feat ----
__global__ void k_final(float* __restrict__ feat, const float* __restrict__ u) {
  size_t i = (size_t)blockIdx.x * 256 + threadIdx.x;  // 9437184
  int b = (int)(i / ((size_t)CHW));
  int yx = (int)(i % HW);
  float f = feat[i];
  float uu = u[b * HW + yx];
  feat[i] = fmaxf(__fadd_rn(__fmul_rn(uu, f), f), 0.f);
}

extern "C" void kernel_launch(void* const* d_in, const int* in_sizes, int n_in,
                              void* d_out, int out_size, void* d_ws, size_t ws_size,
                              hipStream_t stream) {
  const float* wh    = (const float*)d_in[0];
  const float* cnnf  = (const float*)d_in[1];
  const float* c1w   = (const float*)d_in[2];
  const float* c1b   = (const float*)d_in[3];
  const float* c2w   = (const float*)d_in[4];
  const float* c2b   = (const float*)d_in[5];
  const float* wpoly = (const float*)d_in[6];
  const float* wfuse = (const float*)d_in[7];
  const float* bfuse = (const float*)d_in[8];
  const int* ct_ind  = (const int*)d_in[9];
  const int* ct_img  = (const int*)d_in[10];

  float* ws    = (float*)d_ws;
  float* wfT   = ws;               // 131072 fp32
  float* initp = wfT + 131072;     // 32768
  float* coarse= initp + 32768;    // 32768
  float* tmp   = coarse + 32768;   // 65536
  float* u0    = tmp + 65536;      // 147456
  float* u1    = u0 + 147456;      // 147456 (u0,u1 contiguous for k_prep zero)
  float* fpbuf = u1 + 147456;      // 1056768
  unsigned short* wB1 = (unsigned short*)(fpbuf + 1056768);  // 147456 bf16
  unsigned short* wB2 = wB1 + 147456;                        // 16384 bf16
  // total ~6.8 MB

  float* out0 = (float*)d_out;         // init_polys*4   32768
  float* out1 = out0 + 32768;          // coarse*4       32768
  float* out2 = out1 + 32768;          // mb_init        4718592
  float* out3 = out2 + 4718592;        // mb_c           4718592
  float* out4 = out3 + 4718592;        // feat           9437184
  float* feat = out4;                  // feat scratch lives in out4 (fp32)

  k_prep<<<2560, 256, 0, stream>>>(c1w, c2w, wfuse, wB1, wB2, wfT, tmp, u0);
  k_init_polys<<<128, 128, 0, stream>>>(wh, ct_ind, ct_img, initp, out0);
  k_pnp<<<dim3(192, 64), 64, 0, stream>>>(initp, out2, u0);
  k_conv<<<1152, 256, 0, stream>>>(cnnf, wB1, c1b, wB2, c2b, u0, feat);
  k_sample<<<128 * 129, 64, 0, stream>>>(feat, initp, ct_ind, ct_img, fpbuf);
  k_gemm1<<<dim3(2, 8, 16), 256, 0, stream>>>(fpbuf, wpoly, tmp);
  k_gemm2<<<128, 256, 0, stream>>>(tmp, wfT, bfuse, initp, coarse, out1);
  k_pnp<<<dim3(192, 64), 64, 0, stream>>>(coarse, out3, u1);
  k_final<<<36864, 256, 0, stream>>>(feat, u1);
}